// Round 1
// baseline (129.656 us; speedup 1.0000x reference)
//
#include <hip/hip_runtime.h>
#include <hip/hip_bf16.h>

#define N 8192
#define FIN 128
#define FOUT 64

typedef __attribute__((ext_vector_type(4))) float f32x4;
typedef __attribute__((ext_vector_type(4))) int i32x4;
typedef __attribute__((ext_vector_type(8))) short bf16x8;

__device__ __forceinline__ short f2bf(float x) {
    __hip_bfloat16 b = __float2bfloat16(x);
    union { __hip_bfloat16 b; short s; } u; u.b = b; return u.s;
}

// Kernel 1: Wh = h @ W  (store transposed bf16), s_src = Wh@a1, s_dst = Wh@a2 (fp32)
__global__ __launch_bounds__(256) void wh_kernel(
    const float* __restrict__ h, const float* __restrict__ W,
    const float* __restrict__ a,
    __hip_bfloat16* __restrict__ whT, float* __restrict__ s_src,
    float* __restrict__ s_dst) {
    const int wave = threadIdx.x >> 6;
    const int lane = threadIdx.x & 63;   // lane = output feature f
    const int row = blockIdx.x * 4 + wave;
    const float* hr = h + (size_t)row * FIN;
    float acc = 0.f;
#pragma unroll 8
    for (int k = 0; k < FIN; ++k) {
        acc += hr[k] * W[k * FOUT + lane];
    }
    whT[(size_t)lane * N + row] = __float2bfloat16(acc);
    float s1 = acc * a[lane];
    float s2 = acc * a[FOUT + lane];
#pragma unroll
    for (int m = 32; m >= 1; m >>= 1) {
        s1 += __shfl_xor(s1, m, 64);
        s2 += __shfl_xor(s2, m, 64);
    }
    if (lane == 0) { s_src[row] = s1; s_dst[row] = s2; }
}

// Kernel 2: fused masked-softmax attention + P@Wh via MFMA.
// Block = 4 waves; block owns 16 rows; wave w owns j in [w*2048, (w+1)*2048).
// MFMA 16x16x32 bf16: A-frag lane l holds A[l&15][(l>>4)*8 + e];
//                     B-frag lane l holds B[(l>>4)*8 + e][l&15];
//                     D lane l reg r -> D[(l>>4)*4 + r][l&15].
__global__ __launch_bounds__(256) void gat_main(
    const int* __restrict__ adj, const __hip_bfloat16* __restrict__ whT,
    const float* __restrict__ s_src, const float* __restrict__ s_dst,
    float* __restrict__ out) {
    const int tid = threadIdx.x;
    const int w = tid >> 6, lane = tid & 63;
    const int m = lane & 15, kg = lane >> 4;
    const int ibase = blockIdx.x * 16;
    const int row = ibase + m;
    const float ssrc = s_src[row];
    const int jbase = w * (N / 4);

    const int* ap = adj + (size_t)row * N + jbase;
    const float* dp = s_dst + jbase;
    const __hip_bfloat16* wp = whT + (size_t)m * N + jbase;

    f32x4 acc0 = {0,0,0,0}, acc1 = {0,0,0,0}, acc2 = {0,0,0,0}, acc3 = {0,0,0,0};
    float dsum = 0.f;

    const int STEPS = (N / 4) / 32;  // 64
    int jl = kg * 8;

    i32x4 a0 = *(const i32x4*)(ap + jl);
    i32x4 a1 = *(const i32x4*)(ap + jl + 4);
    f32x4 d0 = *(const f32x4*)(dp + jl);
    f32x4 d1 = *(const f32x4*)(dp + jl + 4);
    bf16x8 b0 = *(const bf16x8*)(wp + (size_t)0 * 16 * N + jl);
    bf16x8 b1 = *(const bf16x8*)(wp + (size_t)1 * 16 * N + jl);
    bf16x8 b2 = *(const bf16x8*)(wp + (size_t)2 * 16 * N + jl);
    bf16x8 b3 = *(const bf16x8*)(wp + (size_t)3 * 16 * N + jl);

    for (int s = 0; s < STEPS; ++s) {
        // ---- prefetch next step (clamped address on last iter) ----
        const int jln = (s + 1 < STEPS) ? (jl + 32) : jl;
        i32x4 na0 = *(const i32x4*)(ap + jln);
        i32x4 na1 = *(const i32x4*)(ap + jln + 4);
        f32x4 nd0 = *(const f32x4*)(dp + jln);
        f32x4 nd1 = *(const f32x4*)(dp + jln + 4);
        bf16x8 nb0 = *(const bf16x8*)(wp + (size_t)0 * 16 * N + jln);
        bf16x8 nb1 = *(const bf16x8*)(wp + (size_t)1 * 16 * N + jln);
        bf16x8 nb2 = *(const bf16x8*)(wp + (size_t)2 * 16 * N + jln);
        bf16x8 nb3 = *(const bf16x8*)(wp + (size_t)3 * 16 * N + jln);

        // ---- compute P fragment (fp32 -> bf16), accumulate denominator ----
        bf16x8 afr;
#pragma unroll
        for (int e = 0; e < 4; ++e) {
            float x = ssrc + d0[e];
            x = (x >= 0.f) ? x : 0.2f * x;          // leaky_relu
            float p = (a0[e] > 0) ? __expf(x) : 0.f; // mask -> exp
            dsum += p;
            afr[e] = f2bf(p);
        }
#pragma unroll
        for (int e = 0; e < 4; ++e) {
            float x = ssrc + d1[e];
            x = (x >= 0.f) ? x : 0.2f * x;
            float p = (a1[e] > 0) ? __expf(x) : 0.f;
            dsum += p;
            afr[4 + e] = f2bf(p);
        }

        acc0 = __builtin_amdgcn_mfma_f32_16x16x32_bf16(afr, b0, acc0, 0, 0, 0);
        acc1 = __builtin_amdgcn_mfma_f32_16x16x32_bf16(afr, b1, acc1, 0, 0, 0);
        acc2 = __builtin_amdgcn_mfma_f32_16x16x32_bf16(afr, b2, acc2, 0, 0, 0);
        acc3 = __builtin_amdgcn_mfma_f32_16x16x32_bf16(afr, b3, acc3, 0, 0, 0);

        a0 = na0; a1 = na1; d0 = nd0; d1 = nd1;
        b0 = nb0; b1 = nb1; b2 = nb2; b3 = nb3;
        jl = jln;
    }

    // denominator: combine the 4 k-groups (lanes l, l^16, l^32, l^48 share row m)
    dsum += __shfl_xor(dsum, 16, 64);
    dsum += __shfl_xor(dsum, 32, 64);

    __shared__ float pC[4][16][FOUT];
    __shared__ float pD[4][16];
#pragma unroll
    for (int r = 0; r < 4; ++r) {
        pC[w][kg * 4 + r][0 * 16 + m] = acc0[r];
        pC[w][kg * 4 + r][1 * 16 + m] = acc1[r];
        pC[w][kg * 4 + r][2 * 16 + m] = acc2[r];
        pC[w][kg * 4 + r][3 * 16 + m] = acc3[r];
    }
    if (kg == 0) pD[w][m] = dsum;
    __syncthreads();

    // combine partials across waves, divide, ELU, store
#pragma unroll
    for (int k = 0; k < 4; ++k) {
        int idx = k * 256 + tid;
        int i = idx >> 6, f = idx & 63;
        float num = pC[0][i][f] + pC[1][i][f] + pC[2][i][f] + pC[3][i][f];
        float den = pD[0][i] + pD[1][i] + pD[2][i] + pD[3][i];
        float v = num / den;
        out[(size_t)(ibase + i) * FOUT + f] = (v > 0.f) ? v : expm1f(v);
    }
}

extern "C" void kernel_launch(void* const* d_in, const int* in_sizes, int n_in,
                              void* d_out, int out_size, void* d_ws, size_t ws_size,
                              hipStream_t stream) {
    const float* h = (const float*)d_in[0];
    const int* adj = (const int*)d_in[1];
    const float* W = (const float*)d_in[2];
    const float* a = (const float*)d_in[3];
    float* out = (float*)d_out;

    char* ws = (char*)d_ws;
    __hip_bfloat16* whT = (__hip_bfloat16*)ws;                       // 64*8192*2 = 1 MB
    float* s_src = (float*)(ws + (size_t)FOUT * N * sizeof(__hip_bfloat16));
    float* s_dst = s_src + N;

    hipLaunchKernelGGL(wh_kernel, dim3(N / 4), dim3(256), 0, stream,
                       h, W, a, whT, s_src, s_dst);
    hipLaunchKernelGGL(gat_main, dim3(N / 16), dim3(256), 0, stream,
                       adj, whT, s_src, s_dst, out);
}